// Round 4
// baseline (396.161 us; speedup 1.0000x reference)
//
#include <hip/hip_runtime.h>

#define HWPIX 16384   // 128*128
#define C_IN  512
#define C_HID 256
#define NB    8
#define NK    3       // gland classes 1..3

// ---------------------------------------------------------------------------
// Kernel 1: per-(b,c) masked sums over the HxW plane for classes {1,2,3}.
// One block per (b,c) -> 4096 blocks x 256 threads.
// Feature plane is contiguous -> float4 coalesced loads (64KB/block, from HBM
// exactly once => 268.4 MB total, the roofline term: ~43us @ 6.3 TB/s).
// Mask plane (64KB per b, 512KB total) is L2-resident across the 512 c-blocks
// of each batch: ~256MB of L2 traffic (~7us @ 34.5 TB/s), concurrent with the
// HBM stream; VMEM issue cost ~0.85us/CU -- not a limiter.
// Blocks with c==0 additionally produce the per-batch class counts
// (fused k_counts -- saves one dispatch in the serialized graph).
// unroll 8: ~8 outstanding float4+int4 loads/wave; ~4 waves/SIMD gives ~32MB
// chip-wide in-flight capacity vs ~2.4MB needed (BW x latency) -> not
// latency-bound.
// ---------------------------------------------------------------------------
__global__ __launch_bounds__(256) void k_sums(const float* __restrict__ feat,
                                              const int* __restrict__ mask,
                                              float* __restrict__ sums,
                                              float* __restrict__ counts) {
    const int bc = blockIdx.x;          // b*512 + c
    const int b  = bc >> 9;
    const bool do_counts = (bc & 511) == 0;   // block-uniform branch
    const float4* fp = reinterpret_cast<const float4*>(feat + (size_t)bc * HWPIX);
    const int4*   mp = reinterpret_cast<const int4*>(mask + (size_t)b * HWPIX);

    float s1 = 0.f, s2 = 0.f, s3 = 0.f;
    int   c1 = 0,   c2 = 0,   c3 = 0;

    if (do_counts) {
        #pragma unroll 8
        for (int i = threadIdx.x; i < HWPIX / 4; i += 256) {
            const float4 v = fp[i];
            const int4   m = mp[i];
            s1 += (m.x == 1) ? v.x : 0.f;  s2 += (m.x == 2) ? v.x : 0.f;  s3 += (m.x == 3) ? v.x : 0.f;
            s1 += (m.y == 1) ? v.y : 0.f;  s2 += (m.y == 2) ? v.y : 0.f;  s3 += (m.y == 3) ? v.y : 0.f;
            s1 += (m.z == 1) ? v.z : 0.f;  s2 += (m.z == 2) ? v.z : 0.f;  s3 += (m.z == 3) ? v.z : 0.f;
            s1 += (m.w == 1) ? v.w : 0.f;  s2 += (m.w == 2) ? v.w : 0.f;  s3 += (m.w == 3) ? v.w : 0.f;
            c1 += (m.x == 1) + (m.y == 1) + (m.z == 1) + (m.w == 1);
            c2 += (m.x == 2) + (m.y == 2) + (m.z == 2) + (m.w == 2);
            c3 += (m.x == 3) + (m.y == 3) + (m.z == 3) + (m.w == 3);
        }
    } else {
        #pragma unroll 8
        for (int i = threadIdx.x; i < HWPIX / 4; i += 256) {
            const float4 v = fp[i];
            const int4   m = mp[i];
            s1 += (m.x == 1) ? v.x : 0.f;  s2 += (m.x == 2) ? v.x : 0.f;  s3 += (m.x == 3) ? v.x : 0.f;
            s1 += (m.y == 1) ? v.y : 0.f;  s2 += (m.y == 2) ? v.y : 0.f;  s3 += (m.y == 3) ? v.y : 0.f;
            s1 += (m.z == 1) ? v.z : 0.f;  s2 += (m.z == 2) ? v.z : 0.f;  s3 += (m.z == 3) ? v.z : 0.f;
            s1 += (m.w == 1) ? v.w : 0.f;  s2 += (m.w == 2) ? v.w : 0.f;  s3 += (m.w == 3) ? v.w : 0.f;
        }
    }

    // wave (64-lane) butterfly reduce
    #pragma unroll
    for (int off = 32; off > 0; off >>= 1) {
        s1 += __shfl_down(s1, off, 64);
        s2 += __shfl_down(s2, off, 64);
        s3 += __shfl_down(s3, off, 64);
        if (do_counts) {
            c1 += __shfl_down(c1, off, 64);
            c2 += __shfl_down(c2, off, 64);
            c3 += __shfl_down(c3, off, 64);
        }
    }

    __shared__ float red[4][3];
    __shared__ int   redc[4][3];
    const int wid  = threadIdx.x >> 6;
    const int lane = threadIdx.x & 63;
    if (lane == 0) {
        red[wid][0] = s1; red[wid][1] = s2; red[wid][2] = s3;
        if (do_counts) { redc[wid][0] = c1; redc[wid][1] = c2; redc[wid][2] = c3; }
    }
    __syncthreads();
    if (threadIdx.x == 0) {
        float* o = sums + (size_t)bc * 3;
        o[0] = red[0][0] + red[1][0] + red[2][0] + red[3][0];
        o[1] = red[0][1] + red[1][1] + red[2][1] + red[3][1];
        o[2] = red[0][2] + red[1][2] + red[2][2] + red[3][2];
        if (do_counts) {
            counts[b * 3 + 0] = (float)(redc[0][0] + redc[1][0] + redc[2][0] + redc[3][0]);
            counts[b * 3 + 1] = (float)(redc[0][1] + redc[1][1] + redc[2][1] + redc[3][1]);
            counts[b * 3 + 2] = (float)(redc[0][2] + redc[1][2] + redc[2][2] + redc[3][2]);
        }
    }
}

// ---------------------------------------------------------------------------
// Kernel 2: MLP head. One block per (b,k) row (24 blocks, 256 threads).
// mean[512] staged in LDS; thread j owns hidden unit j (coalesced W1 row
// reads: W1[c*256+j], consecutive j -> consecutive addresses); then 4-logit
// projection via wave reduce. Writes logits + valid flags.
// Output layout: d_out[0..95] = logits [8,3,4]; d_out[96..119] = valid [8,3].
// ---------------------------------------------------------------------------
__global__ __launch_bounds__(256) void k_mlp(const float* __restrict__ sums,
                                             const float* __restrict__ counts,
                                             const float* __restrict__ W1,
                                             const float* __restrict__ b1,
                                             const float* __restrict__ W2,
                                             const float* __restrict__ b2,
                                             float* __restrict__ out) {
    const int bk = blockIdx.x;          // b*3 + k
    const int b  = bk / 3;
    const int k  = bk % 3;

    __shared__ float mean[C_IN];
    __shared__ float redv[4][4];

    const float cnt   = counts[bk];
    const float denom = fmaxf(cnt, 1.0f);

    for (int c = threadIdx.x; c < C_IN; c += 256)
        mean[c] = sums[((size_t)b * C_IN + c) * 3 + k] / denom;
    __syncthreads();

    // hidden unit j = threadIdx.x
    const int j = threadIdx.x;
    float acc = b1[j];
    #pragma unroll 8
    for (int c = 0; c < C_IN; ++c)
        acc = fmaf(mean[c], W1[(size_t)c * C_HID + j], acc);
    const float hj = fmaxf(acc, 0.f);

    // logits: each thread contributes hj * W2[j][o]
    float p0 = hj * W2[j * 4 + 0];
    float p1 = hj * W2[j * 4 + 1];
    float p2 = hj * W2[j * 4 + 2];
    float p3 = hj * W2[j * 4 + 3];
    #pragma unroll
    for (int off = 32; off > 0; off >>= 1) {
        p0 += __shfl_down(p0, off, 64);
        p1 += __shfl_down(p1, off, 64);
        p2 += __shfl_down(p2, off, 64);
        p3 += __shfl_down(p3, off, 64);
    }
    const int wid  = threadIdx.x >> 6;
    const int lane = threadIdx.x & 63;
    if (lane == 0) { redv[wid][0] = p0; redv[wid][1] = p1; redv[wid][2] = p2; redv[wid][3] = p3; }
    __syncthreads();

    if (threadIdx.x < 4) {
        const int o = threadIdx.x;
        const float logit = b2[o] + redv[0][o] + redv[1][o] + redv[2][o] + redv[3][o];
        const bool valid  = cnt > 4.0f;           // MIN_GLAND_SIZE = 4 (strict >)
        out[bk * 4 + o] = valid ? logit : 0.f;
        if (o == 0) out[96 + bk] = valid ? 1.f : 0.f;
    }
}

// ---------------------------------------------------------------------------
extern "C" void kernel_launch(void* const* d_in, const int* in_sizes, int n_in,
                              void* d_out, int out_size, void* d_ws, size_t ws_size,
                              hipStream_t stream) {
    const float* feat = (const float*)d_in[0];   // [8,512,128,128] f32
    const int*   mask = (const int*)d_in[1];     // [8,128,128] i32
    const float* W1   = (const float*)d_in[2];   // [512,256]
    const float* b1   = (const float*)d_in[3];   // [256]
    const float* W2   = (const float*)d_in[4];   // [256,4]
    const float* b2   = (const float*)d_in[5];   // [4]
    float* out = (float*)d_out;                  // 96 logits + 24 valid flags

    float* sums   = (float*)d_ws;                        // 8*512*3 floats = 48 KiB
    float* counts = sums + (size_t)NB * C_IN * NK;       // 24 floats

    k_sums<<<NB * C_IN, 256, 0, stream>>>(feat, mask, sums, counts);
    k_mlp <<<NB * NK,   256, 0, stream>>>(sums, counts, W1, b1, W2, b2, out);
}

// Round 5
// 371.770 us; speedup vs baseline: 1.0656x; 1.0656x over previous
//
#include <hip/hip_runtime.h>

#define HWPIX 16384   // 128*128
#define C_IN  512
#define C_HID 256
#define NB    8
#define NK    3       // gland classes 1..3

// ---------------------------------------------------------------------------
// Kernel 1: masked sums over HxW for classes {1,2,3}, TWO feature planes per
// block (planes 2c and 2c+1 of batch b share the same mask plane -> mask
// VMEM instructions and L1/L2 mask bytes halved vs 1 plane/block).
// Grid 2048 blocks x 256 threads. Feature planes are contiguous (128KB/block)
// -> float4 coalesced loads; features cross HBM exactly once = 268.4 MB,
// floor ~39.5us at the measured-achievable 6.8 TB/s.
// Mask (512KB total) stays L2-resident: ~128MB L2 traffic (~4us @ 34.5TB/s).
// Blocks with cpair==0 also produce per-batch class counts (fused k_counts).
// ---------------------------------------------------------------------------
__global__ __launch_bounds__(256) void k_sums(const float* __restrict__ feat,
                                              const int* __restrict__ mask,
                                              float* __restrict__ sums,
                                              float* __restrict__ counts) {
    const int blk   = blockIdx.x;        // b*256 + cpair
    const int b     = blk >> 8;
    const int cpair = blk & 255;
    const int bc0   = (b << 9) + (cpair << 1);      // first of 2 planes
    const bool do_counts = (cpair == 0);             // block-uniform

    const float4* fp0 = reinterpret_cast<const float4*>(feat + (size_t)bc0 * HWPIX);
    const float4* fp1 = fp0 + HWPIX / 4;
    const int4*   mp  = reinterpret_cast<const int4*>(mask + (size_t)b * HWPIX);

    float a1 = 0.f, a2 = 0.f, a3 = 0.f;   // plane 0 sums
    float d1 = 0.f, d2 = 0.f, d3 = 0.f;   // plane 1 sums
    int   c1 = 0,   c2 = 0,   c3 = 0;

    #pragma unroll 4
    for (int i = threadIdx.x; i < HWPIX / 4; i += 256) {
        const float4 u = fp0[i];
        const float4 v = fp1[i];
        const int4   m = mp[i];
        a1 += (m.x == 1) ? u.x : 0.f;  a2 += (m.x == 2) ? u.x : 0.f;  a3 += (m.x == 3) ? u.x : 0.f;
        a1 += (m.y == 1) ? u.y : 0.f;  a2 += (m.y == 2) ? u.y : 0.f;  a3 += (m.y == 3) ? u.y : 0.f;
        a1 += (m.z == 1) ? u.z : 0.f;  a2 += (m.z == 2) ? u.z : 0.f;  a3 += (m.z == 3) ? u.z : 0.f;
        a1 += (m.w == 1) ? u.w : 0.f;  a2 += (m.w == 2) ? u.w : 0.f;  a3 += (m.w == 3) ? u.w : 0.f;
        d1 += (m.x == 1) ? v.x : 0.f;  d2 += (m.x == 2) ? v.x : 0.f;  d3 += (m.x == 3) ? v.x : 0.f;
        d1 += (m.y == 1) ? v.y : 0.f;  d2 += (m.y == 2) ? v.y : 0.f;  d3 += (m.y == 3) ? v.y : 0.f;
        d1 += (m.z == 1) ? v.z : 0.f;  d2 += (m.z == 2) ? v.z : 0.f;  d3 += (m.z == 3) ? v.z : 0.f;
        d1 += (m.w == 1) ? v.w : 0.f;  d2 += (m.w == 2) ? v.w : 0.f;  d3 += (m.w == 3) ? v.w : 0.f;
        if (do_counts) {
            c1 += (m.x == 1) + (m.y == 1) + (m.z == 1) + (m.w == 1);
            c2 += (m.x == 2) + (m.y == 2) + (m.z == 2) + (m.w == 2);
            c3 += (m.x == 3) + (m.y == 3) + (m.z == 3) + (m.w == 3);
        }
    }

    // wave (64-lane) butterfly reduce
    #pragma unroll
    for (int off = 32; off > 0; off >>= 1) {
        a1 += __shfl_down(a1, off, 64);
        a2 += __shfl_down(a2, off, 64);
        a3 += __shfl_down(a3, off, 64);
        d1 += __shfl_down(d1, off, 64);
        d2 += __shfl_down(d2, off, 64);
        d3 += __shfl_down(d3, off, 64);
        if (do_counts) {
            c1 += __shfl_down(c1, off, 64);
            c2 += __shfl_down(c2, off, 64);
            c3 += __shfl_down(c3, off, 64);
        }
    }

    __shared__ float red[4][6];
    __shared__ int   redc[4][3];
    const int wid  = threadIdx.x >> 6;
    const int lane = threadIdx.x & 63;
    if (lane == 0) {
        red[wid][0] = a1; red[wid][1] = a2; red[wid][2] = a3;
        red[wid][3] = d1; red[wid][4] = d2; red[wid][5] = d3;
        if (do_counts) { redc[wid][0] = c1; redc[wid][1] = c2; redc[wid][2] = c3; }
    }
    __syncthreads();
    if (threadIdx.x == 0) {
        float* o = sums + (size_t)bc0 * 3;
        #pragma unroll
        for (int t = 0; t < 6; ++t)
            o[t] = red[0][t] + red[1][t] + red[2][t] + red[3][t];
        if (do_counts) {
            counts[b * 3 + 0] = (float)(redc[0][0] + redc[1][0] + redc[2][0] + redc[3][0]);
            counts[b * 3 + 1] = (float)(redc[0][1] + redc[1][1] + redc[2][1] + redc[3][1]);
            counts[b * 3 + 2] = (float)(redc[0][2] + redc[1][2] + redc[2][2] + redc[3][2]);
        }
    }
}

// ---------------------------------------------------------------------------
// Kernel 2: MLP head. One block per (b,k) (24 blocks, 1024 threads).
// Only ~1 block/CU, so the old 256-thread version was latency-bound on a
// 512-load chain (1 wave/SIMD). Now 4 waves/SIMD: thread (j = tid&255,
// q = tid>>8) accumulates c in [q*128, q*128+128) -> 128-load chain, LDS
// partial-h reduce across q, then the 4-logit projection via wave reduce.
// Output layout: d_out[0..95] = logits [8,3,4]; d_out[96..119] = valid [8,3].
// ---------------------------------------------------------------------------
__global__ __launch_bounds__(1024) void k_mlp(const float* __restrict__ sums,
                                              const float* __restrict__ counts,
                                              const float* __restrict__ W1,
                                              const float* __restrict__ b1,
                                              const float* __restrict__ W2,
                                              const float* __restrict__ b2,
                                              float* __restrict__ out) {
    const int bk = blockIdx.x;          // b*3 + k
    const int b  = bk / 3;
    const int k  = bk % 3;

    __shared__ float mean[C_IN];
    __shared__ float hpart[4][C_HID];
    __shared__ float redv[4][4];

    const float cnt   = counts[bk];
    const float denom = fmaxf(cnt, 1.0f);

    const int tid = threadIdx.x;
    if (tid < C_IN)
        mean[tid] = sums[((size_t)b * C_IN + tid) * 3 + k] / denom;
    __syncthreads();

    const int j = tid & 255;            // hidden unit
    const int q = tid >> 8;             // c-chunk 0..3
    float acc = (q == 0) ? b1[j] : 0.f;
    const int c0 = q * 128;
    #pragma unroll 8
    for (int c = c0; c < c0 + 128; ++c)
        acc = fmaf(mean[c], W1[(size_t)c * C_HID + j], acc);
    hpart[q][j] = acc;
    __syncthreads();

    if (tid < C_HID) {
        const float hj = fmaxf(hpart[0][j] + hpart[1][j] + hpart[2][j] + hpart[3][j], 0.f);
        float p0 = hj * W2[j * 4 + 0];
        float p1 = hj * W2[j * 4 + 1];
        float p2 = hj * W2[j * 4 + 2];
        float p3 = hj * W2[j * 4 + 3];
        #pragma unroll
        for (int off = 32; off > 0; off >>= 1) {
            p0 += __shfl_down(p0, off, 64);
            p1 += __shfl_down(p1, off, 64);
            p2 += __shfl_down(p2, off, 64);
            p3 += __shfl_down(p3, off, 64);
        }
        const int wid  = tid >> 6;      // 0..3
        if ((tid & 63) == 0) {
            redv[wid][0] = p0; redv[wid][1] = p1; redv[wid][2] = p2; redv[wid][3] = p3;
        }
    }
    __syncthreads();

    if (tid < 4) {
        const int o = tid;
        const float logit = b2[o] + redv[0][o] + redv[1][o] + redv[2][o] + redv[3][o];
        const bool valid  = cnt > 4.0f;           // MIN_GLAND_SIZE = 4 (strict >)
        out[bk * 4 + o] = valid ? logit : 0.f;
        if (o == 0) out[96 + bk] = valid ? 1.f : 0.f;
    }
}

// ---------------------------------------------------------------------------
extern "C" void kernel_launch(void* const* d_in, const int* in_sizes, int n_in,
                              void* d_out, int out_size, void* d_ws, size_t ws_size,
                              hipStream_t stream) {
    const float* feat = (const float*)d_in[0];   // [8,512,128,128] f32
    const int*   mask = (const int*)d_in[1];     // [8,128,128] i32
    const float* W1   = (const float*)d_in[2];   // [512,256]
    const float* b1   = (const float*)d_in[3];   // [256]
    const float* W2   = (const float*)d_in[4];   // [256,4]
    const float* b2   = (const float*)d_in[5];   // [4]
    float* out = (float*)d_out;                  // 96 logits + 24 valid flags

    float* sums   = (float*)d_ws;                        // 8*512*3 floats = 48 KiB
    float* counts = sums + (size_t)NB * C_IN * NK;       // 24 floats

    k_sums<<<NB * C_IN / 2, 256, 0, stream>>>(feat, mask, sums, counts);
    k_mlp <<<NB * NK, 1024, 0, stream>>>(sums, counts, W1, b1, W2, b2, out);
}